// Round 12
// baseline (364.614 us; speedup 1.0000x reference)
//
#include <hip/hip_runtime.h>
#include <hip/hip_bf16.h>

typedef __attribute__((ext_vector_type(8))) short short8;
typedef __attribute__((ext_vector_type(4))) float f32x4;

#define HSZ 128
#define BM  32
#define NT  512
#define GRID 768   // 3 blocks/CU x 256 CU, persistent

// lgkm-only barrier: orders LDS across waves WITHOUT draining vmcnt
// (global stores/loads stay in flight across phases).
#define LGKM_BARRIER() asm volatile("s_waitcnt lgkmcnt(0)\n\ts_barrier" ::: "memory")

__device__ __forceinline__ unsigned short f2bf(float f) {
    union { float f; unsigned int u; } c; c.f = f;
    return (unsigned short)((c.u + 0x7FFFu + ((c.u >> 16) & 1u)) >> 16);
}

// Pack W (bf16) as Wp[col][k] (k contiguous, 16B-aligned fragments).
// W[k][g*128+i] = ih[g*128+k][i] (k<128) else hh[g*128+(k-128)][i].
__global__ void prep_kernel(const float* __restrict__ ih, const float* __restrict__ hh,
                            const float* __restrict__ ib, const float* __restrict__ hb,
                            unsigned short* __restrict__ Wp, float* __restrict__ bias) {
    int tid = blockIdx.x * blockDim.x + threadIdx.x;   // 0..16383
    int col = tid >> 5;                                // 0..511
    int kg  = tid & 31;                                // 0..31
    int g = col >> 7, i = col & 127;
    short8 pk;
    #pragma unroll
    for (int j = 0; j < 8; ++j) {
        int k = kg * 8 + j;
        float v = (k < HSZ) ? ih[(g * HSZ + k) * HSZ + i]
                            : hh[(g * HSZ + (k - HSZ)) * HSZ + i];
        pk[j] = (short)f2bf(v);
    }
    *reinterpret_cast<short8*>(Wp + col * 256 + kg * 8) = pk;
    if (kg == 0) bias[col] = ib[col] + hb[col];
}

__global__ __launch_bounds__(NT, 6)   // <=85 regs -> 6 waves/SIMD = 3 blocks/CU
void lstm_kernel(const float* __restrict__ x, const float* __restrict__ h0,
                 const float* __restrict__ c0,
                 const unsigned short* __restrict__ Wp,
                 const float* __restrict__ biasp,
                 float* __restrict__ out, long BH, int ntiles) {
    constexpr int PITCH = 264;
    __shared__ unsigned short A_lds[BM * PITCH];   // 16.9 KB (separate from T!)
    __shared__ f32x4 T[2][BM * 32];                // 32 KB double buffer

    const int t = threadIdx.x;
    const int lane = t & 63;
    const int wid  = t >> 6;           // 0..7 = 16-col slice within each gate
    const int wn = wid;
    const int lr = lane & 15;
    const int lk = lane >> 4;          // k-group (8 bf16)

    const int fi0 = t;                 // staging flat indices
    const int fi1 = t + NT;

    // ---- prologue: issue first tile's x/h0 loads ----
    int tile = blockIdx.x;
    f32x4 sx0, sx1, sh0, sh1;
    {
        const f32x4* x4 = reinterpret_cast<const f32x4*>(x + (long)tile * BM * HSZ);
        const f32x4* h4 = reinterpret_cast<const f32x4*>(h0 + (long)tile * BM * HSZ);
        sx0 = x4[fi0]; sx1 = x4[fi1];
        sh0 = h4[fi0]; sh1 = h4[fi1];
    }

    // bias fragments are tile-invariant: load once
    f32x4 bg[4];
    #pragma unroll
    for (int g = 0; g < 4; ++g)
        bg[g] = *reinterpret_cast<const f32x4*>(biasp + g * HSZ + wn * 16 + lk * 4);

    const char* Wb = reinterpret_cast<const char*>(Wp) + (wn * 16 + lr) * 512 + lk * 16;
    const char* Ab = reinterpret_cast<const char*>(A_lds) + lr * (PITCH * 2) + lk * 16;

    while (tile < ntiles) {
        const long rowBase = (long)tile * BM;

        // ---- stage A = [x | h0] (32 rows x 256 k) as bf16 into LDS (write-late) ----
        {
            int row0 = fi0 >> 5, c40 = fi0 & 31;
            int row1 = fi1 >> 5, c41 = fi1 & 31;
            ushort4 p;
            p.x = f2bf(sx0.x); p.y = f2bf(sx0.y); p.z = f2bf(sx0.z); p.w = f2bf(sx0.w);
            *reinterpret_cast<ushort4*>(&A_lds[row0 * PITCH + c40 * 4]) = p;
            p.x = f2bf(sx1.x); p.y = f2bf(sx1.y); p.z = f2bf(sx1.z); p.w = f2bf(sx1.w);
            *reinterpret_cast<ushort4*>(&A_lds[row1 * PITCH + c41 * 4]) = p;
            p.x = f2bf(sh0.x); p.y = f2bf(sh0.y); p.z = f2bf(sh0.z); p.w = f2bf(sh0.w);
            *reinterpret_cast<ushort4*>(&A_lds[row0 * PITCH + HSZ + c40 * 4]) = p;
            p.x = f2bf(sh1.x); p.y = f2bf(sh1.y); p.z = f2bf(sh1.z); p.w = f2bf(sh1.w);
            *reinterpret_cast<ushort4*>(&A_lds[row1 * PITCH + HSZ + c41 * 4]) = p;
        }
        LGKM_BARRIER();

        // ---- MFMA: 32 rows x (4 gates x 16 cols) x K=256 ----
        f32x4 acc[2][4] = {};   // [mi][gate]
        #pragma unroll
        for (int ks = 0; ks < 8; ++ks) {
            short8 a0 = *reinterpret_cast<const short8*>(Ab + ks * 64);
            short8 a1 = *reinterpret_cast<const short8*>(Ab + 16 * (PITCH * 2) + ks * 64);
            #pragma unroll
            for (int g = 0; g < 4; ++g) {
                short8 w = *reinterpret_cast<const short8*>(Wb + (g * 128) * 512 + ks * 64);
                acc[0][g] = __builtin_amdgcn_mfma_f32_16x16x32_bf16(w, a0, acc[0][g], 0, 0, 0);
                acc[1][g] = __builtin_amdgcn_mfma_f32_16x16x32_bf16(w, a1, acc[1][g], 0, 0, 0);
            }
        }

        // ---- c0 fragment loads (consumed at P4) ----
        f32x4 c0v[2];
        #pragma unroll
        for (int mi = 0; mi < 2; ++mi) {
            long pos = (rowBase + mi * 16 + lr) * HSZ + wn * 16 + lk * 4;
            c0v[mi] = *reinterpret_cast<const f32x4*>(c0 + pos);
        }

        // ---- fold bias ----
        #pragma unroll
        for (int g = 0; g < 4; ++g) { acc[0][g] += bg[g]; acc[1][g] += bg[g]; }

        // ---- issue NEXT tile's x/h0 loads (hide under epilogue stores) ----
        int ntile = tile + GRID;
        if (ntile < ntiles) {
            const f32x4* x4 = reinterpret_cast<const f32x4*>(x + (long)ntile * BM * HSZ);
            const f32x4* h4 = reinterpret_cast<const f32x4*>(h0 + (long)ntile * BM * HSZ);
            sx0 = x4[fi0]; sx1 = x4[fi1];
            sh0 = h4[fi0]; sh1 = h4[fi1];
        }

        LGKM_BARRIER();   // staging A-reads done block-wide; T safe to reuse

        #define SIDX(MI) ((MI * 16 + lr) * 32 + ((wn * 4 + lk) ^ (lr & 7)))
        auto flush = [&](const f32x4* Tb, long obase) {
            #pragma unroll
            for (int p = 0; p < 2; ++p) {
                int f = t + p * NT;               // 0..1023 granules
                int row = f >> 5, c = f & 31;
                f32x4 v = Tb[row * 32 + (c ^ (row & 7))];
                __builtin_nontemporal_store(v,
                    reinterpret_cast<f32x4*>(out + obase + (rowBase + row) * (long)HSZ + c * 4));
            }
        };

        // ---- P0: I -> T0 ----
        #pragma unroll
        for (int mi = 0; mi < 2; ++mi) T[0][SIDX(mi)] = acc[mi][0];
        LGKM_BARRIER();
        // ---- P1: flush I || F -> T1 ----
        flush(T[0], 2 * BH);
        #pragma unroll
        for (int mi = 0; mi < 2; ++mi) T[1][SIDX(mi)] = acc[mi][1];
        LGKM_BARRIER();
        // ---- P2: flush F || G -> T0 ----
        flush(T[1], 3 * BH);
        #pragma unroll
        for (int mi = 0; mi < 2; ++mi) T[0][SIDX(mi)] = acc[mi][2];
        LGKM_BARRIER();
        // ---- P3: flush G || O -> T1 ----
        flush(T[0], 4 * BH);
        #pragma unroll
        for (int mi = 0; mi < 2; ++mi) T[1][SIDX(mi)] = acc[mi][3];
        LGKM_BARRIER();
        // ---- P4: flush O || c_1 -> T0 ----
        flush(T[1], 5 * BH);
        #pragma unroll
        for (int mi = 0; mi < 2; ++mi) {
            f32x4 v;
            #pragma unroll
            for (int r = 0; r < 4; ++r) {
                float iv = acc[mi][0][r];
                float fv = acc[mi][1][r];
                float gv = acc[mi][2][r];
                float si = 1.f / (1.f + __expf(-iv));
                float sf = 1.f / (1.f + __expf(-fv));
                float tg = 1.f - 2.f / (__expf(2.f * gv) + 1.f);
                v[r] = c0v[mi][r] * sf + si * tg;
            }
            T[0][SIDX(mi)] = v;
        }
        LGKM_BARRIER();
        // ---- P5: flush c_1 || h_1 -> T1 ----
        flush(T[0], BH);
        #pragma unroll
        for (int mi = 0; mi < 2; ++mi) {
            f32x4 c1 = T[0][SIDX(mi)];
            f32x4 v;
            #pragma unroll
            for (int r = 0; r < 4; ++r) {
                float ov = acc[mi][3][r];
                float so = 1.f / (1.f + __expf(-ov));
                float th = 1.f - 2.f / (__expf(2.f * c1[r]) + 1.f);
                v[r] = so + th;
            }
            T[1][SIDX(mi)] = v;
        }
        LGKM_BARRIER();
        // ---- P6: flush h_1 (stores stay in flight into next tile) ----
        flush(T[1], 0);
        #undef SIDX

        tile = ntile;
    }
}

extern "C" void kernel_launch(void* const* d_in, const int* in_sizes, int n_in,
                              void* d_out, int out_size, void* d_ws, size_t ws_size,
                              hipStream_t stream) {
    const float* x  = (const float*)d_in[0];
    const float* h0 = (const float*)d_in[1];
    const float* c0 = (const float*)d_in[2];
    const float* ih = (const float*)d_in[3];
    const float* hh = (const float*)d_in[4];
    const float* ib = (const float*)d_in[5];
    const float* hb = (const float*)d_in[6];
    float* out = (float*)d_out;

    unsigned short* Wp = (unsigned short*)d_ws;            // 512*256 bf16 = 256 KB
    float* bias = (float*)((char*)d_ws + 512 * 256 * 2);   // 512 f32

    long BH = in_sizes[2];      // B * H
    int ntiles = (int)(BH / HSZ / BM);

    prep_kernel<<<64, 256, 0, stream>>>(ih, hh, ib, hb, Wp, bias);
    lstm_kernel<<<GRID, NT, 0, stream>>>(x, h0, c0, Wp, bias, out, BH, ntiles);
}

// Round 13
// 306.634 us; speedup vs baseline: 1.1891x; 1.1891x over previous
//
#include <hip/hip_runtime.h>
#include <hip/hip_bf16.h>

typedef __attribute__((ext_vector_type(8))) short short8;
typedef __attribute__((ext_vector_type(4))) float f32x4;

#define HSZ 128
#define BM  32
#define NT  1024

// lgkm-only barrier: orders LDS across waves WITHOUT draining vmcnt.
#define LGKM_BARRIER() asm volatile("s_waitcnt lgkmcnt(0)\n\ts_barrier" ::: "memory")

__device__ __forceinline__ unsigned short f2bf(float f) {
    union { float f; unsigned int u; } c; c.f = f;
    return (unsigned short)((c.u + 0x7FFFu + ((c.u >> 16) & 1u)) >> 16);
}

// Pack W (bf16) as Wp[col][k] (k contiguous, 16B-aligned fragments).
// W[k][g*128+i] = ih[g*128+k][i] (k<128) else hh[g*128+(k-128)][i].
__global__ void prep_kernel(const float* __restrict__ ih, const float* __restrict__ hh,
                            const float* __restrict__ ib, const float* __restrict__ hb,
                            unsigned short* __restrict__ Wp, float* __restrict__ bias) {
    int tid = blockIdx.x * blockDim.x + threadIdx.x;   // 0..16383
    int col = tid >> 5;                                // 0..511
    int kg  = tid & 31;                                // 0..31
    int g = col >> 7, i = col & 127;
    short8 pk;
    #pragma unroll
    for (int j = 0; j < 8; ++j) {
        int k = kg * 8 + j;
        float v = (k < HSZ) ? ih[(g * HSZ + k) * HSZ + i]
                            : hh[(g * HSZ + (k - HSZ)) * HSZ + i];
        pk[j] = (short)f2bf(v);
    }
    *reinterpret_cast<short8*>(Wp + col * 256 + kg * 8) = pk;
    if (kg == 0) bias[col] = ib[col] + hb[col];
}

union SMem {
    unsigned short A[BM * 264];   // 16.9 KB bf16 activations (dead after MFMA)
    f32x4 T[2][BM * 32];          // 2 x 16 KB f32 output tiles (double buffer)
};

__global__ __launch_bounds__(NT, 8)   // <=64 regs -> 8 waves/SIMD = 2 blocks/CU = 100%
void lstm_kernel(const float* __restrict__ x, const float* __restrict__ h0,
                 const float* __restrict__ c0,
                 const unsigned short* __restrict__ Wp,
                 const float* __restrict__ biasp,
                 float* __restrict__ out, long BH) {
    constexpr int PITCH = 264;
    __shared__ SMem sm;

    const int t = threadIdx.x;
    const long rowBase = (long)blockIdx.x * BM;

    // ---- stage A = [x | h0] (32 rows x 256 k) as bf16 into LDS ----
    {
        const float4* x4 = reinterpret_cast<const float4*>(x + rowBase * HSZ);
        const float4* h4 = reinterpret_cast<const float4*>(h0 + rowBase * HSZ);
        int row = t >> 5;
        int c4  = t & 31;
        float4 vx = x4[t];
        float4 vh = h4[t];
        ushort4 px; px.x = f2bf(vx.x); px.y = f2bf(vx.y); px.z = f2bf(vx.z); px.w = f2bf(vx.w);
        ushort4 ph; ph.x = f2bf(vh.x); ph.y = f2bf(vh.y); ph.z = f2bf(vh.z); ph.w = f2bf(vh.w);
        *reinterpret_cast<ushort4*>(&sm.A[row * PITCH + c4 * 4]) = px;
        *reinterpret_cast<ushort4*>(&sm.A[row * PITCH + HSZ + c4 * 4]) = ph;
    }
    LGKM_BARRIER();

    const int lane = t & 63;
    const int wid  = t >> 6;           // 0..15
    const int wm = wid & 1;            // row half (16 rows)
    const int ws = wid >> 1;           // 0..7: 16-col slice within each gate
    const int lr = lane & 15;
    const int lk = lane >> 4;          // k-group (8 bf16)

    const char* Ab = reinterpret_cast<const char*>(sm.A)
                   + (wm * 16 + lr) * (PITCH * 2) + lk * 16;
    const char* Wb = reinterpret_cast<const char*>(Wp) + (ws * 16 + lr) * 512 + lk * 16;

    f32x4 acc[4] = {};   // [gate], 16 AGPR

    #pragma unroll
    for (int ks = 0; ks < 8; ++ks) {
        short8 a0 = *reinterpret_cast<const short8*>(Ab + ks * 64);
        #pragma unroll
        for (int g = 0; g < 4; ++g) {
            short8 w = *reinterpret_cast<const short8*>(Wb + (g * 128) * 512 + ks * 64);
            // Swapped operands: D col = batch row (lr), lane's 4 regs = gate cols lk*4+r
            acc[g] = __builtin_amdgcn_mfma_f32_16x16x32_bf16(w, a0, acc[g], 0, 0, 0);
        }
    }

    // ---- c0 fragment load (consumed at P4) ----
    f32x4 c0v;
    {
        long pos = (rowBase + wm * 16 + lr) * HSZ + ws * 16 + lk * 4;
        c0v = *reinterpret_cast<const f32x4*>(c0 + pos);
    }

    // ---- fold bias ----
    #pragma unroll
    for (int g = 0; g < 4; ++g)
        acc[g] += *reinterpret_cast<const f32x4*>(biasp + g * HSZ + ws * 16 + lk * 4);

    LGKM_BARRIER();   // A tile dead; LDS becomes output double-buffer

    // PUT slot: row = wm*16+lr, granule col = ws*4+lk, XOR-swizzled by row&7
    const int sidx = (wm * 16 + lr) * 32 + ((ws * 4 + lk) ^ ((wm * 16 + lr) & 7));

    // flush: 1024 threads x 16B = one full 16-KB plane per call
    auto flush = [&](const f32x4* Tb, long obase) {
        int row = t >> 5, c = t & 31;
        f32x4 v = Tb[row * 32 + (c ^ (row & 7))];
        __builtin_nontemporal_store(v,
            reinterpret_cast<f32x4*>(out + obase + (rowBase + row) * (long)HSZ + c * 4));
    };

    // ---- P0: I -> T0 ----
    sm.T[0][sidx] = acc[0];
    LGKM_BARRIER();
    // ---- P1: flush I || F -> T1 ----
    flush(sm.T[0], 2 * BH);
    sm.T[1][sidx] = acc[1];
    LGKM_BARRIER();
    // ---- P2: flush F || G -> T0 ----
    flush(sm.T[1], 3 * BH);
    sm.T[0][sidx] = acc[2];
    LGKM_BARRIER();
    // ---- P3: flush G || O -> T1 ----
    flush(sm.T[0], 4 * BH);
    sm.T[1][sidx] = acc[3];
    LGKM_BARRIER();
    // ---- P4: flush O || c_1 -> T0 (exp-heavy compute in store shadow) ----
    flush(sm.T[1], 5 * BH);
    {
        f32x4 v;
        #pragma unroll
        for (int r = 0; r < 4; ++r) {
            float iv = acc[0][r];
            float fv = acc[1][r];
            float gv = acc[2][r];
            float si = 1.f / (1.f + __expf(-iv));
            float sf = 1.f / (1.f + __expf(-fv));
            float tg = 1.f - 2.f / (__expf(2.f * gv) + 1.f);
            v[r] = c0v[r] * sf + si * tg;
        }
        sm.T[0][sidx] = v;
    }
    LGKM_BARRIER();
    // ---- P5: flush c_1 || h_1 -> T1 (c_1 read back from own T0 slot) ----
    flush(sm.T[0], BH);
    {
        f32x4 c1 = sm.T[0][sidx];
        f32x4 v;
        #pragma unroll
        for (int r = 0; r < 4; ++r) {
            float ov = acc[3][r];
            float so = 1.f / (1.f + __expf(-ov));
            float th = 1.f - 2.f / (__expf(2.f * c1[r]) + 1.f);
            v[r] = so + th;
        }
        sm.T[1][sidx] = v;
    }
    LGKM_BARRIER();
    // ---- P6: flush h_1 (stores drain at endpgm) ----
    flush(sm.T[1], 0);
}

extern "C" void kernel_launch(void* const* d_in, const int* in_sizes, int n_in,
                              void* d_out, int out_size, void* d_ws, size_t ws_size,
                              hipStream_t stream) {
    const float* x  = (const float*)d_in[0];
    const float* h0 = (const float*)d_in[1];
    const float* c0 = (const float*)d_in[2];
    const float* ih = (const float*)d_in[3];
    const float* hh = (const float*)d_in[4];
    const float* ib = (const float*)d_in[5];
    const float* hb = (const float*)d_in[6];
    float* out = (float*)d_out;

    unsigned short* Wp = (unsigned short*)d_ws;            // 512*256 bf16 = 256 KB
    float* bias = (float*)((char*)d_ws + 512 * 256 * 2);   // 512 f32

    long BH = in_sizes[2];      // B * H
    long B  = BH / HSZ;

    prep_kernel<<<64, 256, 0, stream>>>(ih, hh, ib, hb, Wp, bias);
    lstm_kernel<<<(int)(B / BM), NT, 0, stream>>>(x, h0, c0, Wp, bias, out, BH);
}

// Round 14
// 194.400 us; speedup vs baseline: 1.8756x; 1.5773x over previous
//
#include <hip/hip_runtime.h>
#include <hip/hip_bf16.h>

typedef __attribute__((ext_vector_type(8))) short short8;
typedef __attribute__((ext_vector_type(4))) float f32x4;

#define HSZ 128
#define BM  32
#define NT  512

// lgkm-only barrier: orders LDS across waves WITHOUT draining vmcnt
// (global stores stay in flight across phases).
#define LGKM_BARRIER() asm volatile("s_waitcnt lgkmcnt(0)\n\ts_barrier" ::: "memory")

__device__ __forceinline__ unsigned short f2bf(float f) {
    union { float f; unsigned int u; } c; c.f = f;
    return (unsigned short)((c.u + 0x7FFFu + ((c.u >> 16) & 1u)) >> 16);
}

// Pack W (bf16) as Wp[col][k] (k contiguous, 16B-aligned fragments).
// W[k][g*128+i] = ih[g*128+k][i] (k<128) else hh[g*128+(k-128)][i].
__global__ void prep_kernel(const float* __restrict__ ih, const float* __restrict__ hh,
                            const float* __restrict__ ib, const float* __restrict__ hb,
                            unsigned short* __restrict__ Wp, float* __restrict__ bias) {
    int tid = blockIdx.x * blockDim.x + threadIdx.x;   // 0..16383
    int col = tid >> 5;                                // 0..511
    int kg  = tid & 31;                                // 0..31
    int g = col >> 7, i = col & 127;
    short8 pk;
    #pragma unroll
    for (int j = 0; j < 8; ++j) {
        int k = kg * 8 + j;
        float v = (k < HSZ) ? ih[(g * HSZ + k) * HSZ + i]
                            : hh[(g * HSZ + (k - HSZ)) * HSZ + i];
        pk[j] = (short)f2bf(v);
    }
    *reinterpret_cast<short8*>(Wp + col * 256 + kg * 8) = pk;
    if (kg == 0) bias[col] = ib[col] + hb[col];
}

union SMem {
    unsigned short A[BM * 264];   // 16.9 KB bf16 activations (dead after MFMA)
    f32x4 T[2][BM * 32];          // 2 x 16 KB f32 output tiles (double buffer)
};

__global__ __launch_bounds__(NT, 6)   // <=85 regs -> 6 waves/SIMD = 3 blocks/CU
void lstm_kernel(const float* __restrict__ x, const float* __restrict__ h0,
                 const float* __restrict__ c0,
                 const unsigned short* __restrict__ Wp,
                 const float* __restrict__ biasp,
                 float* __restrict__ out, long BH, int cpx) {
    constexpr int PITCH = 264;
    __shared__ SMem sm;

    const int t = threadIdx.x;
    // XCD-aware bijective swizzle: each XCD gets a contiguous chunk of tiles
    // (grid % 8 == 0 guaranteed by launcher). Contiguous per-XCD write-back.
    const int bid = blockIdx.x;
    const int tile = (bid & 7) * cpx + (bid >> 3);
    const long rowBase = (long)tile * BM;

    // ---- stage A = [x | h0] (32 rows x 256 k) as bf16 into LDS ----
    {
        const float4* x4 = reinterpret_cast<const float4*>(x + rowBase * HSZ);
        const float4* h4 = reinterpret_cast<const float4*>(h0 + rowBase * HSZ);
        #pragma unroll
        for (int j = 0; j < 2; ++j) {
            int fi = t + j * NT;               // 0..1023
            int row = fi >> 5;
            int c4  = fi & 31;
            float4 vx = x4[fi];
            float4 vh = h4[fi];
            ushort4 px; px.x = f2bf(vx.x); px.y = f2bf(vx.y); px.z = f2bf(vx.z); px.w = f2bf(vx.w);
            ushort4 ph; ph.x = f2bf(vh.x); ph.y = f2bf(vh.y); ph.z = f2bf(vh.z); ph.w = f2bf(vh.w);
            *reinterpret_cast<ushort4*>(&sm.A[row * PITCH + c4 * 4]) = px;
            *reinterpret_cast<ushort4*>(&sm.A[row * PITCH + HSZ + c4 * 4]) = ph;
        }
    }
    LGKM_BARRIER();

    const int lane = t & 63;
    const int wid  = t >> 6;           // 0..7 = 16-col slice within each gate
    const int wn = wid;
    const int lr = lane & 15;
    const int lk = lane >> 4;          // k-group (8 bf16)

    const char* Ab = reinterpret_cast<const char*>(sm.A) + lr * (PITCH * 2) + lk * 16;
    const char* Wb = reinterpret_cast<const char*>(Wp) + (wn * 16 + lr) * 512 + lk * 16;

    f32x4 acc[2][4] = {};   // [mi][gate], 32 AGPR

    #pragma unroll
    for (int ks = 0; ks < 8; ++ks) {
        short8 a0 = *reinterpret_cast<const short8*>(Ab + ks * 64);
        short8 a1 = *reinterpret_cast<const short8*>(Ab + 16 * (PITCH * 2) + ks * 64);
        #pragma unroll
        for (int g = 0; g < 4; ++g) {
            short8 w = *reinterpret_cast<const short8*>(Wb + (g * 128) * 512 + ks * 64);
            // Swapped operands: D col = batch row (lr), lane's 4 regs = gate cols lk*4+r
            acc[0][g] = __builtin_amdgcn_mfma_f32_16x16x32_bf16(w, a0, acc[0][g], 0, 0, 0);
            acc[1][g] = __builtin_amdgcn_mfma_f32_16x16x32_bf16(w, a1, acc[1][g], 0, 0, 0);
        }
    }

    // ---- c0 fragment loads (consumed at P4; long slack) ----
    f32x4 c0v[2];
    #pragma unroll
    for (int mi = 0; mi < 2; ++mi) {
        long pos = (rowBase + mi * 16 + lr) * HSZ + wn * 16 + lk * 4;
        c0v[mi] = *reinterpret_cast<const f32x4*>(c0 + pos);
    }

    // ---- fold bias into acc ----
    #pragma unroll
    for (int g = 0; g < 4; ++g) {
        f32x4 bg = *reinterpret_cast<const f32x4*>(biasp + g * HSZ + wn * 16 + lk * 4);
        acc[0][g] += bg;
        acc[1][g] += bg;
    }

    LGKM_BARRIER();   // A tile dead; LDS becomes output double-buffer

    // granule col for PUT: 0..31 = wn*4 + lk; XOR-swizzled by row&7
    #define SIDX(MI) ((MI * 16 + lr) * 32 + ((wn * 4 + lk) ^ (lr & 7)))

    auto flush = [&](const f32x4* T, long obase) {
        #pragma unroll
        for (int p = 0; p < 2; ++p) {
            int f = t + p * NT;               // 0..1023 granules
            int row = f >> 5, c = f & 31;
            f32x4 v = T[row * 32 + (c ^ (row & 7))];
            __builtin_nontemporal_store(v,
                reinterpret_cast<f32x4*>(out + obase + (rowBase + row) * (long)HSZ + c * 4));
        }
    };

    // ---- P0: I -> T0 ----
    #pragma unroll
    for (int mi = 0; mi < 2; ++mi) sm.T[0][SIDX(mi)] = acc[mi][0];
    LGKM_BARRIER();

    // ---- P1: flush I || F -> T1 ----
    flush(sm.T[0], 2 * BH);
    #pragma unroll
    for (int mi = 0; mi < 2; ++mi) sm.T[1][SIDX(mi)] = acc[mi][1];
    LGKM_BARRIER();

    // ---- P2: flush F || G -> T0 ----
    flush(sm.T[1], 3 * BH);
    #pragma unroll
    for (int mi = 0; mi < 2; ++mi) sm.T[0][SIDX(mi)] = acc[mi][2];
    LGKM_BARRIER();

    // ---- P3: flush G || O -> T1 ----
    flush(sm.T[0], 4 * BH);
    #pragma unroll
    for (int mi = 0; mi < 2; ++mi) sm.T[1][SIDX(mi)] = acc[mi][3];
    LGKM_BARRIER();

    // ---- P4: flush O || c_1 -> T0 (exp-heavy compute in store shadow) ----
    flush(sm.T[1], 5 * BH);
    #pragma unroll
    for (int mi = 0; mi < 2; ++mi) {
        f32x4 v;
        #pragma unroll
        for (int r = 0; r < 4; ++r) {
            float iv = acc[mi][0][r];
            float fv = acc[mi][1][r];
            float gv = acc[mi][2][r];
            float si = 1.f / (1.f + __expf(-iv));
            float sf = 1.f / (1.f + __expf(-fv));
            float tg = 1.f - 2.f / (__expf(2.f * gv) + 1.f);
            v[r] = c0v[mi][r] * sf + si * tg;
        }
        sm.T[0][SIDX(mi)] = v;
    }
    LGKM_BARRIER();

    // ---- P5: flush c_1 || h_1 -> T1 (c_1 read back from own T0 slot) ----
    flush(sm.T[0], BH);
    #pragma unroll
    for (int mi = 0; mi < 2; ++mi) {
        f32x4 c1 = sm.T[0][SIDX(mi)];
        f32x4 v;
        #pragma unroll
        for (int r = 0; r < 4; ++r) {
            float ov = acc[mi][3][r];
            float so = 1.f / (1.f + __expf(-ov));
            float th = 1.f - 2.f / (__expf(2.f * c1[r]) + 1.f);
            v[r] = so + th;
        }
        sm.T[1][SIDX(mi)] = v;
    }
    LGKM_BARRIER();

    // ---- P6: flush h_1 (no trailing drain needed before endpgm) ----
    flush(sm.T[1], 0);
    #undef SIDX
}

extern "C" void kernel_launch(void* const* d_in, const int* in_sizes, int n_in,
                              void* d_out, int out_size, void* d_ws, size_t ws_size,
                              hipStream_t stream) {
    const float* x  = (const float*)d_in[0];
    const float* h0 = (const float*)d_in[1];
    const float* c0 = (const float*)d_in[2];
    const float* ih = (const float*)d_in[3];
    const float* hh = (const float*)d_in[4];
    const float* ib = (const float*)d_in[5];
    const float* hb = (const float*)d_in[6];
    float* out = (float*)d_out;

    unsigned short* Wp = (unsigned short*)d_ws;            // 512*256 bf16 = 256 KB
    float* bias = (float*)((char*)d_ws + 512 * 256 * 2);   // 512 f32

    long BH = in_sizes[2];      // B * H
    long B  = BH / HSZ;
    int nwg = (int)(B / BM);    // 4096: divisible by 8 -> bijective swizzle
    int cpx = nwg / 8;

    prep_kernel<<<64, 256, 0, stream>>>(ih, hh, ib, hb, Wp, bias);
    lstm_kernel<<<nwg, NT, 0, stream>>>(x, h0, c0, Wp, bias, out, BH, cpx);
}